// Round 1
// baseline (639.629 us; speedup 1.0000x reference)
//
#include <hip/hip_runtime.h>

// ---------- types ----------
typedef __attribute__((ext_vector_type(8))) short bf16x8;   // MFMA A/B frag (8 bf16)
typedef __attribute__((ext_vector_type(4))) float f32x4;    // MFMA C/D frag

// ---------- math helpers ----------
__device__ __forceinline__ short f2bf(float f) {
  unsigned u = __float_as_uint(f);
  u += 0x7fffu + ((u >> 16) & 1u);          // round-to-nearest-even
  return (short)(u >> 16);
}
__device__ __forceinline__ float bf2f(short s) {
  return __uint_as_float(((unsigned)(unsigned short)s) << 16);
}
__device__ __forceinline__ float sigm(float z) {
  return __builtin_amdgcn_rcpf(1.f + __builtin_amdgcn_exp2f(-1.44269504089f * z));
}
__device__ __forceinline__ float tanh_(float z) {
  // tanh(z) = 1 - 2/(1+e^{2z})
  return 1.f - 2.f * __builtin_amdgcn_rcpf(1.f + __builtin_amdgcn_exp2f(2.88539008178f * z));
}

// ---------- geometry ----------
// Components: node M=50000, edge M=100000, glob M=512. d=128, T=8.
// ws layout per component (stride 140800 B):
//   mat m in {W1a,W1b,W2,W3}: bf16 WT[128 cols][136 kpad]  (34816 B each)
//   biases: 384 f32 (b1,b2,b3) at +139264
#define KP 136                    // padded K leading dim (shorts); 272 B rows, 16B-aligned
#define MAT_SH (128 * KP)         // shorts per matrix = 17408
#define WS_COMP 140800            // bytes per component block in ws
#define NODE_BLOCKS 782
#define EDGE_BLOCKS 1563
#define GLOB_BLOCKS 8
#define NBLOCKS (NODE_BLOCKS + EDGE_BLOCKS + GLOB_BLOCKS)   // 2353

// prep: one component per launch; block m handles matrix m; block 0 also biases.
__global__ __launch_bounds__(256) void prep_weights(
    const float* __restrict__ W1, const float* __restrict__ b1,
    const float* __restrict__ W2, const float* __restrict__ b2,
    const float* __restrict__ W3, const float* __restrict__ b3,
    unsigned char* __restrict__ wsc) {
  const int m = blockIdx.x;  // 0=W1a 1=W1b 2=W2 3=W3
  short* dst = (short*)wsc + m * MAT_SH;
  const float* src;
  int rowoff = 0;
  if (m == 0)      { src = W1; rowoff = 0; }
  else if (m == 1) { src = W1; rowoff = 128; }
  else if (m == 2) { src = W2; }
  else             { src = W3; }
  for (int e = threadIdx.x; e < 16384; e += 256) {
    int k = e >> 7, col = e & 127;            // coalesced read
    dst[col * KP + k] = f2bf(src[(size_t)(k + rowoff) * 128 + col]);
  }
  for (int e = threadIdx.x; e < 1024; e += 256) {  // zero the pad
    int col = e >> 3, kp = 128 + (e & 7);
    dst[col * KP + kp] = 0;
  }
  if (m == 0) {
    float* bd = (float*)(wsc + 4 * MAT_SH * 2);
    for (int i = threadIdx.x; i < 384; i += 256) {
      float v = (i < 128) ? b1[i] : (i < 256) ? b2[i - 128] : b3[i - 256];
      bd[i] = v;
    }
  }
}

// main fused recurrent kernel
__global__ __launch_bounds__(256, 1) void glstm(
    const float* __restrict__ xs, const float* __restrict__ es,
    const float* __restrict__ gs, const unsigned char* __restrict__ ws,
    float* __restrict__ dout) {
  // LDS: 4 matrices (139264 B) + biases (1536 B) + 4 per-wave staging (4x4352 B)
  __shared__ __align__(16) unsigned char smem[158208];

  const int bid = blockIdx.x;
  const int tid = threadIdx.x;

  const float* X; float* S; float* O; long M; int unit, cb;
  if (bid < NODE_BLOCKS) {
    X = xs; M = 50000;  S = dout;             O = dout + 19265536L; unit = bid; cb = 0;
  } else if (bid < NODE_BLOCKS + EDGE_BLOCKS) {
    X = es; M = 100000; S = dout + 6400000L;  O = dout + 25665536L; unit = bid - NODE_BLOCKS; cb = 1;
  } else {
    X = gs; M = 512;    S = dout + 19200000L; O = dout + 38465536L; unit = bid - (NODE_BLOCKS + EDGE_BLOCKS); cb = 2;
  }

  // stage weights+biases ws -> LDS (140800 B = 8800 uint4)
  {
    const uint4* src = (const uint4*)(ws + (size_t)cb * WS_COMP);
    uint4* dst = (uint4*)smem;
    for (int i = tid; i < 8800; i += 256) dst[i] = src[i];
  }
  __syncthreads();

  const int w = tid >> 6, l = tid & 63;
  const int c = l & 15, g = l >> 4;
  const long R = (long)unit * 64 + w * 16;
  if (R >= M) return;

  const short* wmat = (const short*)smem;                    // [4][128][KP]
  const float* blds = (const float*)(smem + 4 * MAT_SH * 2); // 384 f32
  short* stg = (short*)(smem + WS_COMP) + w * (16 * KP);     // per-wave [16][KP]

  // biases in registers (col = 16*ct + c)
  float b1v[8], b2v[8], b3v[8];
#pragma unroll
  for (int ct = 0; ct < 8; ++ct) {
    b1v[ct] = blds[16 * ct + c];
    b2v[ct] = blds[128 + 16 * ct + c];
    b3v[ct] = blds[256 + 16 * ct + c];
  }

  // init carry: state = out = x[0]  (C/D layout: row 4g+ri, col 16ct+c)
  f32x4 st[8], ot[8];
#pragma unroll
  for (int ct = 0; ct < 8; ++ct) {
#pragma unroll
    for (int ri = 0; ri < 4; ++ri) {
      float v = X[(size_t)(R + 4 * g + ri) * 128 + 16 * ct + c];
      st[ct][ri] = v; ot[ct][ri] = v;
    }
  }

  for (int t = 0; t < 8; ++t) {
    const float* Xt = X + (size_t)t * M * 128;

    // 1. stage out -> LDS as bf16 [row][k]
#pragma unroll
    for (int ct = 0; ct < 8; ++ct)
#pragma unroll
      for (int ri = 0; ri < 4; ++ri)
        stg[(4 * g + ri) * KP + 16 * ct + c] = f2bf(ot[ct][ri]);

    // 2. issue x A-frag global loads (row R+c, k-chunk 32kc+8g)
    const float* xrow = Xt + (size_t)(R + c) * 128 + 8 * g;
    f32x4 xa[4][2];
#pragma unroll
    for (int kc = 0; kc < 4; ++kc) {
      xa[kc][0] = *(const f32x4*)(xrow + 32 * kc);
      xa[kc][1] = *(const f32x4*)(xrow + 32 * kc + 4);
    }

    // 3. out A-frags from staging
    bf16x8 of[4];
#pragma unroll
    for (int kc = 0; kc < 4; ++kc)
      of[kc] = *(const bf16x8*)(stg + c * KP + 32 * kc + 8 * g);

    // 4. accA = out @ W1a
    f32x4 accA[8];
#pragma unroll
    for (int ct = 0; ct < 8; ++ct) {
      accA[ct] = (f32x4){0.f, 0.f, 0.f, 0.f};
#pragma unroll
      for (int kc = 0; kc < 4; ++kc)
        accA[ct] = __builtin_amdgcn_mfma_f32_16x16x32_bf16(
            of[kc],
            *(const bf16x8*)(wmat + 0 * MAT_SH + (16 * ct + c) * KP + 32 * kc + 8 * g),
            accA[ct], 0, 0, 0);
    }

    // 5. convert x to bf16 frags
    bf16x8 xf[4];
#pragma unroll
    for (int kc = 0; kc < 4; ++kc) {
#pragma unroll
      for (int j = 0; j < 4; ++j) {
        xf[kc][j]     = f2bf(xa[kc][0][j]);
        xf[kc][4 + j] = f2bf(xa[kc][1][j]);
      }
    }
    // 6. stage x frags (overwrites out staging; wave-local ordering is safe)
#pragma unroll
    for (int kc = 0; kc < 4; ++kc)
      *(bf16x8*)(stg + c * KP + 32 * kc + 8 * g) = xf[kc];

    // 7-9. accA += x@W1b ; accB = x@W2 ; accC = x@W3
    f32x4 accB[8], accC[8];
#pragma unroll
    for (int ct = 0; ct < 8; ++ct) {
#pragma unroll
      for (int kc = 0; kc < 4; ++kc)
        accA[ct] = __builtin_amdgcn_mfma_f32_16x16x32_bf16(
            xf[kc],
            *(const bf16x8*)(wmat + 1 * MAT_SH + (16 * ct + c) * KP + 32 * kc + 8 * g),
            accA[ct], 0, 0, 0);
      accB[ct] = (f32x4){0.f, 0.f, 0.f, 0.f};
#pragma unroll
      for (int kc = 0; kc < 4; ++kc)
        accB[ct] = __builtin_amdgcn_mfma_f32_16x16x32_bf16(
            xf[kc],
            *(const bf16x8*)(wmat + 2 * MAT_SH + (16 * ct + c) * KP + 32 * kc + 8 * g),
            accB[ct], 0, 0, 0);
      accC[ct] = (f32x4){0.f, 0.f, 0.f, 0.f};
#pragma unroll
      for (int kc = 0; kc < 4; ++kc)
        accC[ct] = __builtin_amdgcn_mfma_f32_16x16x32_bf16(
            xf[kc],
            *(const bf16x8*)(wmat + 3 * MAT_SH + (16 * ct + c) * KP + 32 * kc + 8 * g),
            accC[ct], 0, 0, 0);
    }

    // 10. elementwise update (x read back from staging in C/D layout)
#pragma unroll
    for (int ct = 0; ct < 8; ++ct) {
#pragma unroll
      for (int ri = 0; ri < 4; ++ri) {
        float xe = bf2f(stg[(4 * g + ri) * KP + 16 * ct + c]);
        float f  = sigm(accA[ct][ri] + b1v[ct]);
        float s2 = sigm(accB[ct][ri] + b2v[ct]);
        st[ct][ri] = st[ct][ri] * f + s2 * tanh_(xe);
        ot[ct][ri] = tanh_(st[ct][ri]) * sigm(accC[ct][ri] + b3v[ct]);
      }
    }
  }

  // store state & out (f32)
#pragma unroll
  for (int ct = 0; ct < 8; ++ct) {
#pragma unroll
    for (int ri = 0; ri < 4; ++ri) {
      size_t off = (size_t)(R + 4 * g + ri) * 128 + 16 * ct + c;
      S[off] = st[ct][ri];
      O[off] = ot[ct][ri];
    }
  }
}

extern "C" void kernel_launch(void* const* d_in, const int* in_sizes, int n_in,
                              void* d_out, int out_size, void* d_ws, size_t ws_size,
                              hipStream_t stream) {
  (void)in_sizes; (void)n_in; (void)out_size; (void)ws_size;
  const float* xs = (const float*)d_in[0];
  const float* es = (const float*)d_in[1];
  const float* gs = (const float*)d_in[2];
  unsigned char* ws = (unsigned char*)d_ws;

  for (int comp = 0; comp < 3; ++comp) {
    const float* W1 = (const float*)d_in[3 + comp * 6 + 0];
    const float* b1 = (const float*)d_in[3 + comp * 6 + 1];
    const float* W2 = (const float*)d_in[3 + comp * 6 + 2];
    const float* b2 = (const float*)d_in[3 + comp * 6 + 3];
    const float* W3 = (const float*)d_in[3 + comp * 6 + 4];
    const float* b3 = (const float*)d_in[3 + comp * 6 + 5];
    prep_weights<<<4, 256, 0, stream>>>(W1, b1, W2, b2, W3, b3,
                                        ws + (size_t)comp * WS_COMP);
  }
  glstm<<<NBLOCKS, 256, 0, stream>>>(xs, es, gs, ws, (float*)d_out);
}